// Round 1
// 1571.748 us; speedup vs baseline: 1.6754x; 1.6754x over previous
//
#include <hip/hip_runtime.h>
#include <math.h>

#define B 32
#define NS 384
#define H 6
#define DH 64
#define LAYERS 4
#define CACHE_T 447
#define SELF_T 448
#define CROSS_T 1500
#define VOCAB 51865
#define SCALE 0.125f

// ---------------------------------------------------------------------------
// ws layout (floats):
//   xbuf  @ 0       [32][384]   residual stream x
//   xlnT  @ 12288   [384][32]   final-LN output, transposed (for logits)
//   qbuf  @ 24576   [32][384]   q projection
//   h1T   @ 49152   [1536][32]  MLP hidden, transposed
//   po    @ 98304   [32][6][6][64]  flash partial O
//   pml   @ 172032  [32][6][6][2]   flash partial (m, l)
// total 174,336 floats = 697 KB
// ---------------------------------------------------------------------------

// ===========================================================================
// Generic projection engine: y[b][n] = sum_d src_ln_or_combined[d][b] * W[d][n]
// One block = 64 n-lanes x 4 waves; each wave owns a 96-wide D-slice (so the
// dependent-load chain is 96/32 = 3 groups of 32 in-flight HBM loads, not
// 384/4 = 96 groups like the old gemv). x (or combined attn O, or h1 slice)
// is staged into LDS as xls[d][b] (stride 36 floats: 144B, 16B-aligned).
// SRC: 0 = LayerNorm(src[b][d]) with lng/lnb
//      2 = softmax split-combine of (po, pml) with S splits
//      3 = slice hsrc[(hd0+d)*32 + b]  (MLP hidden)
// OUTM: 0 = dst[b*dstride + n] (+bias, +resid)
//       1 = transposed dst[n*32 + b] (+bias, GELU)  (MLP hidden write)
//       2 = atomicAdd into dst[b*NS + n] (+bias only when wd0 == 0)
// ===========================================================================
template <int SRC, int OUTM, bool GELU>
__device__ __forceinline__ void proj_core(
    const float* __restrict__ src, const float* __restrict__ lng, const float* __restrict__ lnb,
    const float* __restrict__ po, const float* __restrict__ pml, int S,
    const float* __restrict__ hsrc, int hd0,
    const float* __restrict__ W, int wstride, int wd0,
    const float* __restrict__ bias, const float* __restrict__ resid,
    float* __restrict__ dst, int dstride) {
    __shared__ __align__(16) float smem[13824 + 1280];
    float* xls = smem;            // [384][36]
    float* wn = smem + 13824;     // [192][6] combine weights (SRC==2)
    int tid = threadIdx.x;
    int wv = tid >> 6;   // wave 0..3
    int lane = tid & 63;

    // ---- stage xls[d*36 + b] ----
    if (SRC == 0) {
        // fused LayerNorm: wave wv handles rows wv*8 .. wv*8+7; 8 lanes per row
        int r = wv * 8 + (lane >> 3);
        int part = lane & 7;                       // 48-element segment of the row
        const float4* xr = (const float4*)(src + (size_t)r * NS + part * 48);
        float4 a[12];
        float sum = 0.f, sq = 0.f;
#pragma unroll
        for (int j = 0; j < 12; ++j) {
            float4 t = xr[j];
            a[j] = t;
            sum += t.x + t.y + t.z + t.w;
            sq += t.x * t.x + t.y * t.y + t.z * t.z + t.w * t.w;
        }
        sum += __shfl_xor(sum, 1); sq += __shfl_xor(sq, 1);
        sum += __shfl_xor(sum, 2); sq += __shfl_xor(sq, 2);
        sum += __shfl_xor(sum, 4); sq += __shfl_xor(sq, 4);
        float mean = sum * (1.0f / NS);
        float rstd = rsqrtf(sq * (1.0f / NS) - mean * mean + 1e-5f);
        const float4* g4 = (const float4*)(lng + part * 48);
        const float4* be4 = (const float4*)(lnb + part * 48);
#pragma unroll
        for (int j = 0; j < 12; ++j) {
            float4 gv = g4[j], bv = be4[j];
            int d = part * 48 + j * 4;
            xls[(d + 0) * 36 + r] = (a[j].x - mean) * rstd * gv.x + bv.x;
            xls[(d + 1) * 36 + r] = (a[j].y - mean) * rstd * gv.y + bv.y;
            xls[(d + 2) * 36 + r] = (a[j].z - mean) * rstd * gv.z + bv.z;
            xls[(d + 3) * 36 + r] = (a[j].w - mean) * rstd * gv.w + bv.w;
        }
    } else if (SRC == 2) {
        // fused flash combine: per (b,h) normalized split weights, then O[d][b]
        if (tid < 192) {  // tid enumerates bh = b*6+h
            int base = tid * 6;
            float M = -1e30f;
            for (int s2 = 0; s2 < S; ++s2) M = fmaxf(M, pml[(base + s2) * 2]);
            float L = 0.f;
            float wvv[6];
            for (int s2 = 0; s2 < S; ++s2) {
                wvv[s2] = expf(pml[(base + s2) * 2] - M);
                L += pml[(base + s2) * 2 + 1] * wvv[s2];
            }
            float inv = 1.0f / L;
            for (int s2 = 0; s2 < S; ++s2) wn[tid * 6 + s2] = wvv[s2] * inv;
        }
        __syncthreads();
        for (int i = 0; i < 16; ++i) {
            int idx = i * 256 + tid;     // 4096 slots: 32 b x 128 (96 used)
            int bb = idx >> 7;
            int c4 = idx & 127;
            if (c4 < 96) {
                int d = c4 * 4;
                int h = d >> 6, dh = d & 63;
                int bh = bb * 6 + h;
                float4 o = {0.f, 0.f, 0.f, 0.f};
                for (int s2 = 0; s2 < S; ++s2) {
                    float w = wn[bh * 6 + s2];
                    float4 p = *(const float4*)(po + ((size_t)(bh * 6 + s2)) * 64 + dh);
                    o.x += w * p.x; o.y += w * p.y; o.z += w * p.z; o.w += w * p.w;
                }
                xls[(d + 0) * 36 + bb] = o.x;
                xls[(d + 1) * 36 + bb] = o.y;
                xls[(d + 2) * 36 + bb] = o.z;
                xls[(d + 3) * 36 + bb] = o.w;
            }
        }
    } else {  // SRC == 3: contiguous [384][32] slice of h1T
        const float4* hp = (const float4*)(hsrc + (size_t)hd0 * 32);
        for (int i = 0; i < 12; ++i) {
            int idx = i * 256 + tid;   // 3072 float4
            float4 v = hp[idx];
            int d = idx >> 3;
            int b4 = (idx & 7) * 4;
            *((float4*)(xls + d * 36 + b4)) = v;
        }
    }
    __syncthreads();

    // ---- main GEMV: wave wv covers d in [wv*96, wv*96+96), 32 loads in flight ----
    float acc[32];
#pragma unroll
    for (int b = 0; b < 32; ++b) acc[b] = 0.f;
    int n = blockIdx.x * 64 + lane;
    const float* wp = W + (size_t)(wd0 + wv * 96) * wstride + n;
    const float* xr = xls + (wv * 96) * 36;
#pragma unroll 1
    for (int dd = 0; dd < 96; dd += 32) {
        float wregs[32];
#pragma unroll
        for (int u = 0; u < 32; ++u) wregs[u] = wp[(size_t)(dd + u) * wstride];
#pragma unroll
        for (int u = 0; u < 32; ++u) {
            const float* row = xr + (dd + u) * 36;
#pragma unroll
            for (int b4 = 0; b4 < 8; ++b4) {
                float4 xv = *(const float4*)(row + b4 * 4);
                acc[b4 * 4 + 0] += xv.x * wregs[u];
                acc[b4 * 4 + 1] += xv.y * wregs[u];
                acc[b4 * 4 + 2] += xv.z * wregs[u];
                acc[b4 * 4 + 3] += xv.w * wregs[u];
            }
        }
    }
    __syncthreads();  // all waves done reading xls -> safe to alias as red

    // ---- cross-wave reduce via LDS (stride 33: conflict-free) ----
    float* red = smem;
#pragma unroll
    for (int b = 0; b < 32; ++b) red[(wv * 64 + lane) * 33 + b] = acc[b];
    __syncthreads();

    if (OUTM == 1) {
#pragma unroll
        for (int j = 0; j < 8; ++j) {
            int idx = tid * 8 + j;
            int l = idx >> 5, bb = idx & 31;
            float s2 = red[l * 33 + bb] + red[(64 + l) * 33 + bb] +
                       red[(128 + l) * 33 + bb] + red[(192 + l) * 33 + bb];
            int nn = blockIdx.x * 64 + l;
            float y = s2 + (bias ? bias[nn] : 0.f);
            if (GELU) y = 0.5f * y * (1.f + erff(y * 0.70710678118654752f));
            dst[(size_t)nn * 32 + bb] = y;
        }
    } else {
#pragma unroll
        for (int j = 0; j < 8; ++j) {
            int idx = tid * 8 + j;
            int bb = idx >> 6, l = idx & 63;
            float s2 = red[l * 33 + bb] + red[(64 + l) * 33 + bb] +
                       red[(128 + l) * 33 + bb] + red[(192 + l) * 33 + bb];
            int nn = blockIdx.x * 64 + l;
            if (OUTM == 0) {
                float y = s2 + (bias ? bias[nn] : 0.f);
                if (resid) y += resid[(size_t)bb * NS + nn];
                dst[(size_t)bb * dstride + nn] = y;
            } else {  // OUTM == 2
                float y = s2 + ((wd0 == 0 && bias) ? bias[nn] : 0.f);
                atomicAdd(dst + (size_t)bb * NS + nn, y);
            }
        }
    }
}

// fused LN + {Q,K,V} projections; blockIdx.y selects the matrix
__global__ __launch_bounds__(256) void qkv_kernel(
    const float* __restrict__ src, const float* __restrict__ lng, const float* __restrict__ lnb,
    const float* __restrict__ W0, const float* __restrict__ bb0, float* __restrict__ dd0, int s0,
    const float* __restrict__ W1p, const float* __restrict__ bb1, float* __restrict__ dd1, int s1,
    const float* __restrict__ W2p, const float* __restrict__ bb2, float* __restrict__ dd2, int s2) {
    const float* W;
    const float* bias;
    float* dst;
    int ds;
    if (blockIdx.y == 0) { W = W0; bias = bb0; dst = dd0; ds = s0; }
    else if (blockIdx.y == 1) { W = W1p; bias = bb1; dst = dd1; ds = s1; }
    else { W = W2p; bias = bb2; dst = dd2; ds = s2; }
    proj_core<0, 0, false>(src, lng, lnb, nullptr, nullptr, 0, nullptr, 0,
                           W, NS, 0, bias, nullptr, dst, ds);
}

// fused flash-combine + o-projection + residual add
__global__ __launch_bounds__(256) void oproj_kernel(
    const float* __restrict__ po, const float* __restrict__ pml, int S,
    const float* __restrict__ W, const float* __restrict__ bias,
    const float* __restrict__ resid, float* __restrict__ dst) {
    proj_core<2, 0, false>(nullptr, nullptr, nullptr, po, pml, S, nullptr, 0,
                           W, NS, 0, bias, resid, dst, NS);
}

// fused LN + W1 + exact GELU, transposed output h1T[1536][32]
__global__ __launch_bounds__(256) void mlp1_kernel(
    const float* __restrict__ src, const float* __restrict__ lng, const float* __restrict__ lnb,
    const float* __restrict__ W, const float* __restrict__ bias, float* __restrict__ dst) {
    proj_core<0, 1, true>(src, lng, lnb, nullptr, nullptr, 0, nullptr, 0,
                          W, 4 * NS, 0, bias, nullptr, dst, 0);
}

// split-K W2 projection, atomicAdd into residual x; bias added by split 0
__global__ __launch_bounds__(256) void mlp2_kernel(
    const float* __restrict__ hsrc, const float* __restrict__ W,
    const float* __restrict__ bias, float* __restrict__ dst) {
    int d0 = blockIdx.y * 384;
    proj_core<3, 2, false>(nullptr, nullptr, nullptr, nullptr, nullptr, 0, hsrc, d0,
                           W, NS, d0, bias, nullptr, dst, NS);
}

// ===========================================================================
// flash-decoding partial; COPY=true additionally streams the KV cache from
// the original inputs into out_ks/out_vs (rows < CACHE_T), fusing the cache
// copy with the attention read (saves one full 176 MB read pass + a kernel).
// Rows >= CACHE_T (the new token) are read from the out buffer (written by
// qkv_kernel).
// ===========================================================================
template <bool COPY>
__global__ __launch_bounds__(256) void attn_partial2(
    const float* __restrict__ q,
    const float* __restrict__ kin, const float* __restrict__ vin, int in_bstride,
    float* __restrict__ kout, float* __restrict__ vout, int out_bstride,
    int chunk, float* __restrict__ po, float* __restrict__ pml) {
    int b = blockIdx.x, h = blockIdx.y, s = blockIdx.z;
    int tid = threadIdx.x;  // 256
    __shared__ __align__(16) float q_s[DH];
    __shared__ float sc[256];
    __shared__ float red[256];
    __shared__ float avred[4][DH];
    if (tid < DH) q_s[tid] = q[b * NS + h * DH + tid];
    __syncthreads();
    int k0 = s * chunk;
    const float* kpin = kin + (size_t)b * in_bstride + h * DH;

    // scores: 16 threads per key (4 floats each), 16 keys per iteration
    int kk = tid >> 4;
    int dq = (tid & 15) * 4;
    float4 qv = *(const float4*)(q_s + dq);
    for (int base = 0; base < chunk; base += 16) {
        int k = base + kk;
        float sv = 0.f;
        if (k < chunk) {
            int row = k0 + k;
            float4 kv;
            if (COPY) {
                if (row < CACHE_T) {
                    kv = *(const float4*)(kpin + (size_t)row * NS + dq);
                    *(float4*)(kout + (size_t)b * out_bstride + (size_t)row * NS + h * DH + dq) = kv;
                } else {
                    kv = *(const float4*)(kout + (size_t)b * out_bstride + (size_t)row * NS + h * DH + dq);
                }
            } else {
                kv = *(const float4*)(kpin + (size_t)row * NS + dq);
            }
            sv = kv.x * qv.x + kv.y * qv.y + kv.z * qv.z + kv.w * qv.w;
        }
        sv += __shfl_xor(sv, 8);
        sv += __shfl_xor(sv, 4);
        sv += __shfl_xor(sv, 2);
        sv += __shfl_xor(sv, 1);
        if ((tid & 15) == 0 && k < chunk) sc[k] = sv * SCALE;
    }
    __syncthreads();

    // local max
    float mv = (tid < chunk) ? sc[tid] : -1e30f;
    red[tid] = mv;
    __syncthreads();
    for (int off = 128; off > 0; off >>= 1) {
        if (tid < off) red[tid] = fmaxf(red[tid], red[tid + off]);
        __syncthreads();
    }
    float m = red[0];
    __syncthreads();

    // exp + local sum
    float ps = 0.f;
    if (tid < chunk) {
        ps = expf(sc[tid] - m);
        sc[tid] = ps;
    }
    red[tid] = ps;
    __syncthreads();
    for (int off = 128; off > 0; off >>= 1) {
        if (tid < off) red[tid] += red[tid + off];
        __syncthreads();
    }
    float l = red[0];

    // AV: 4 key-groups x 64 dims (fused V copy on the same pass)
    int dh = tid & 63;
    int g = tid >> 6;
    const float* vpin = vin + (size_t)b * in_bstride + h * DH + dh;
    float acc = 0.f;
#pragma unroll 4
    for (int k = g; k < chunk; k += 4) {
        int row = k0 + k;
        float vv;
        if (COPY) {
            if (row < CACHE_T) {
                vv = vpin[(size_t)row * NS];
                vout[(size_t)b * out_bstride + (size_t)row * NS + h * DH + dh] = vv;
            } else {
                vv = vout[(size_t)b * out_bstride + (size_t)row * NS + h * DH + dh];
            }
        } else {
            vv = vpin[(size_t)row * NS];
        }
        acc += sc[k] * vv;
    }
    avred[g][dh] = acc;
    __syncthreads();
    if (tid < DH) {
        float o = avred[0][tid] + avred[1][tid] + avred[2][tid] + avred[3][tid];
        int idx = (b * H + h) * 6 + s;
        po[(size_t)idx * DH + tid] = o;
        if (tid == 0) {
            pml[idx * 2 + 0] = m;
            pml[idx * 2 + 1] = l;
        }
    }
}

// LayerNorm over 384, one block (128 threads) per batch row; writes TRANSPOSED xlnT[d][b]
__global__ void ln_kernel(const float* __restrict__ x, const float* __restrict__ g,
                          const float* __restrict__ beta, float* __restrict__ xlnT) {
    int b = blockIdx.x;
    int tid = threadIdx.x;  // 128
    __shared__ float s_sum[128], s_sq[128];
    float v0 = x[b * NS + tid];
    float v1 = x[b * NS + tid + 128];
    float v2 = x[b * NS + tid + 256];
    s_sum[tid] = v0 + v1 + v2;
    s_sq[tid] = v0 * v0 + v1 * v1 + v2 * v2;
    __syncthreads();
    for (int off = 64; off > 0; off >>= 1) {
        if (tid < off) {
            s_sum[tid] += s_sum[tid + off];
            s_sq[tid] += s_sq[tid + off];
        }
        __syncthreads();
    }
    float m = s_sum[0] * (1.0f / NS);
    float var = s_sq[0] * (1.0f / NS) - m * m;
    float rs = rsqrtf(var + 1e-5f);
    xlnT[(tid)*B + b]         = (v0 - m) * rs * g[tid]       + beta[tid];
    xlnT[(tid + 128) * B + b] = (v1 - m) * rs * g[tid + 128] + beta[tid + 128];
    xlnT[(tid + 256) * B + b] = (v2 - m) * rs * g[tid + 256] + beta[tid + 256];
}

// logits[b][v] = sum_d xT[d][b] * Wout[v][d]; one vocab row per thread, 32 batch accumulators
__global__ void logits_kernel(const float* __restrict__ xT, const float* __restrict__ Wout,
                              float* __restrict__ out) {
    int v = blockIdx.x * 256 + threadIdx.x;
    if (v >= VOCAB) return;
    float acc[32];
#pragma unroll
    for (int b = 0; b < 32; ++b) acc[b] = 0.f;
    const float4* wr = (const float4*)(Wout + (size_t)v * NS);
    for (int d4 = 0; d4 < NS / 4; ++d4) {
        float4 w = wr[d4];
        const float* x0 = xT + (size_t)(d4 * 4) * B;
#pragma unroll
        for (int b = 0; b < 32; ++b) {
            acc[b] += x0[b] * w.x + x0[b + B] * w.y + x0[b + 2 * B] * w.z + x0[b + 3 * B] * w.w;
        }
    }
#pragma unroll
    for (int b = 0; b < 32; ++b) out[(size_t)b * VOCAB + v] = acc[b];
}

extern "C" void kernel_launch(void* const* d_in, const int* in_sizes, int n_in,
                              void* d_out, int out_size, void* d_ws, size_t ws_size,
                              hipStream_t stream) {
    const float* te = (const float*)d_in[0];
    const float *crossk[4], *crossv[4], *selfk[4], *selfv[4];
    for (int i = 0; i < 4; ++i) {
        crossk[i] = (const float*)d_in[1 + 2 * i];
        crossv[i] = (const float*)d_in[2 + 2 * i];
        selfk[i] = (const float*)d_in[9 + 2 * i];
        selfv[i] = (const float*)d_in[10 + 2 * i];
    }
    const float* ln_g = (const float*)d_in[17];
    const float* ln_b = (const float*)d_in[18];
    const float* Wq = (const float*)d_in[19];
    const float* bq = (const float*)d_in[20];
    const float* Wk = (const float*)d_in[21];
    const float* Wv = (const float*)d_in[22];
    const float* bv = (const float*)d_in[23];
    const float* Wo = (const float*)d_in[24];
    const float* bo = (const float*)d_in[25];
    const float* cln_g = (const float*)d_in[26];
    const float* cln_b = (const float*)d_in[27];
    const float* cWq = (const float*)d_in[28];
    const float* cbq = (const float*)d_in[29];
    const float* cWo = (const float*)d_in[30];
    const float* cbo = (const float*)d_in[31];
    const float* mln_g = (const float*)d_in[32];
    const float* mln_b = (const float*)d_in[33];
    const float* W1 = (const float*)d_in[34];
    const float* b1 = (const float*)d_in[35];
    const float* W2 = (const float*)d_in[36];
    const float* b2 = (const float*)d_in[37];
    const float* lnf_g = (const float*)d_in[38];
    const float* lnf_b = (const float*)d_in[39];
    const float* Wout = (const float*)d_in[40];

    float* out = (float*)d_out;
    float* out_logits = out;
    float* out_ks = out + (size_t)B * VOCAB;
    float* out_vs = out_ks + (size_t)LAYERS * B * SELF_T * NS;

    float* ws = (float*)d_ws;
    float* xbuf = ws;
    float* xlnT = ws + 12288;
    float* qbuf = ws + 24576;
    float* h1T = ws + 49152;
    float* po = ws + 98304;
    float* pml = ws + 172032;

    for (int i = 0; i < LAYERS; ++i) {
        const float* Wq_i = Wq + (size_t)i * NS * NS;
        const float* Wk_i = Wk + (size_t)i * NS * NS;
        const float* Wv_i = Wv + (size_t)i * NS * NS;
        const float* Wo_i = Wo + (size_t)i * NS * NS;
        const float* cWq_i = cWq + (size_t)i * NS * NS;
        const float* cWo_i = cWo + (size_t)i * NS * NS;
        const float* W1_i = W1 + (size_t)i * NS * 4 * NS;
        const float* W2_i = W2 + (size_t)i * 4 * NS * NS;
        float* ks_l = out_ks + (size_t)i * B * SELF_T * NS;
        float* vs_l = out_vs + (size_t)i * B * SELF_T * NS;
        const float* x_src = (i == 0) ? te : xbuf;

        // --- self-attention block ---
        // fused LN + Q/K/V projections (k/v new-token rows written straight
        // into the output cache at row CACHE_T)
        qkv_kernel<<<dim3(6, 3), 256, 0, stream>>>(
            x_src, ln_g + i * NS, ln_b + i * NS,
            Wq_i, bq + i * NS, qbuf, NS,
            Wk_i, nullptr, ks_l + (size_t)CACHE_T * NS, SELF_T * NS,
            Wv_i, bv + i * NS, vs_l + (size_t)CACHE_T * NS, SELF_T * NS);
        // flash partials, fused with the cache copy (inputs -> out_ks/out_vs)
        attn_partial2<true><<<dim3(32, 6, 4), 256, 0, stream>>>(
            qbuf, selfk[i], selfv[i], CACHE_T * NS,
            ks_l, vs_l, SELF_T * NS, 112, po, pml);
        // fused combine + o-projection + residual
        oproj_kernel<<<6, 256, 0, stream>>>(po, pml, 4, Wo_i, bo + i * NS, x_src, xbuf);

        // --- cross-attention block ---
        qkv_kernel<<<dim3(6, 1), 256, 0, stream>>>(
            xbuf, cln_g + i * NS, cln_b + i * NS,
            cWq_i, cbq + i * NS, qbuf, NS,
            nullptr, nullptr, nullptr, 0,
            nullptr, nullptr, nullptr, 0);
        attn_partial2<false><<<dim3(32, 6, 6), 256, 0, stream>>>(
            qbuf, crossk[i], crossv[i], CROSS_T * NS,
            nullptr, nullptr, 0, 250, po, pml);
        oproj_kernel<<<6, 256, 0, stream>>>(po, pml, 6, cWo_i, cbo + i * NS, xbuf, xbuf);

        // --- MLP block ---
        mlp1_kernel<<<24, 256, 0, stream>>>(xbuf, mln_g + i * NS, mln_b + i * NS,
                                            W1_i, b1 + i * 4 * NS, h1T);
        mlp2_kernel<<<dim3(6, 4), 256, 0, stream>>>(h1T, W2_i, b2 + i * NS, xbuf);
    }

    ln_kernel<<<32, 128, 0, stream>>>(xbuf, lnf_g, lnf_b, xlnT);
    logits_kernel<<<203, 256, 0, stream>>>(xlnT, Wout, out_logits);
}